// Round 2
// baseline (17644.057 us; speedup 1.0000x reference)
//
#include <hip/hip_runtime.h>
#include <hip/hip_bf16.h>

#define NBATCH 16384
#define NJ 15
#define DIM 128
#define NH 16
#define HSZ 8
#define DEPTH 6
#define HID 64
#define QK_SCALE 0.6f
#define LN_EPS 1e-5f
#define NT 512

__device__ __forceinline__ float wave_sum(float v) {
#pragma unroll
  for (int o = 32; o; o >>= 1) v += __shfl_xor(v, o);
  return v;
}

// LayerNorm over DIM=128 for rows r0, r0+rstep, ... (one wave per row; lane covers 2 cols)
__device__ __forceinline__ void ln_rows(const float (*__restrict__ src)[DIM],
                                        float (*__restrict__ dst)[DIM],
                                        const float* __restrict__ w,
                                        const float* __restrict__ bb,
                                        int r0, int rstep, int lane) {
  for (int r = r0; r < NJ; r += rstep) {
    float v0 = src[r][lane], v1 = src[r][lane + 64];
    float m = wave_sum(v0 + v1) * (1.0f / DIM);
    float d0 = v0 - m, d1 = v1 - m;
    float var = wave_sum(d0 * d0 + d1 * d1) * (1.0f / DIM);
    float rstd = rsqrtf(var + LN_EPS);
    dst[r][lane]      = d0 * rstd * w[lane]      + bb[lane];
    dst[r][lane + 64] = d1 * rstd * w[lane + 64] + bb[lane + 64];
  }
}

// A[15][128] @ W[128][384] + bias -> dst[15][384]; one thread per output column j.
__device__ __forceinline__ void gemm384(const float (*__restrict__ A)[DIM],
                                        const float* __restrict__ W,
                                        const float* __restrict__ bias,
                                        float (*__restrict__ dst)[3 * DIM], int j) {
  float acc[NJ];
#pragma unroll
  for (int n = 0; n < NJ; ++n) acc[n] = 0.f;
#pragma unroll 2
  for (int k = 0; k < DIM; k += 4) {
    float w0 = W[(k + 0) * (3 * DIM) + j];
    float w1 = W[(k + 1) * (3 * DIM) + j];
    float w2 = W[(k + 2) * (3 * DIM) + j];
    float w3 = W[(k + 3) * (3 * DIM) + j];
#pragma unroll
    for (int n = 0; n < NJ; ++n) {
      float4 a = *reinterpret_cast<const float4*>(&A[n][k]);
      acc[n] += a.x * w0 + a.y * w1 + a.z * w2 + a.w * w3;
    }
  }
  float bj = bias[j];
#pragma unroll
  for (int n = 0; n < NJ; ++n) dst[n][j] = acc[n] + bj;
}

__global__ __launch_bounds__(NT, 1) void jrt_fused(
    const float* __restrict__ jf, const float* __restrict__ rf,
    const float* __restrict__ Jw, const float* __restrict__ Jb,
    const float* __restrict__ Iw, const float* __restrict__ Ib,
    const float* __restrict__ Cw, const float* __restrict__ Cb,
    const float* __restrict__ Pw, const float* __restrict__ Pb,
    const float* __restrict__ L1w, const float* __restrict__ L1b,
    const float* __restrict__ L2w, const float* __restrict__ L2b,
    const float* __restrict__ L3w, const float* __restrict__ L3b,
    const float* __restrict__ F1w, const float* __restrict__ F1b,
    const float* __restrict__ F2w, const float* __restrict__ F2b,
    float* __restrict__ out) {
  __shared__ float sx[NJ][DIM];     // residual stream
  __shared__ float srel[NJ][DIM];   // relation feature (persistent)
  __shared__ float sa1[NJ][DIM];    // jn / ln3 out
  __shared__ float sa2[NJ][DIM];    // rn
  __shared__ float sqJ[NJ][3 * DIM];
  __shared__ float sqI[NJ][3 * DIM];
  __shared__ float ssc[NH][NJ][NJ]; // attention scores / probs
  __shared__ float sy[NJ][DIM];     // attn output
  __shared__ float sh1[NJ][HID];    // fc1 output

  const int t = threadIdx.x;
  const int wave = t >> 6;
  const int lane = t & 63;
  const int b = blockIdx.x;

  // ---- load x, rel (coalesced)
  {
    const float* jfp = jf + (size_t)b * (NJ * DIM);
    const float* rfp = rf + (size_t)b * (NJ * DIM);
    float* xflat = &sx[0][0];
    float* rflat = &srel[0][0];
    for (int i = t; i < NJ * DIM; i += NT) {
      xflat[i] = jfp[i];
      rflat[i] = rfp[i];
    }
  }
  __syncthreads();

  for (int L = 0; L < DEPTH; ++L) {
    const float* Jw_l = Jw + (size_t)L * DIM * 3 * DIM;
    const float* Jb_l = Jb + L * 3 * DIM;
    const float* Iw_l = Iw + (size_t)L * DIM * 3 * DIM;
    const float* Ib_l = Ib + L * 3 * DIM;
    const float* Cw_l = Cw + L * HSZ * NJ;
    const float* Cb_l = Cb + L * NJ;
    const float* Pw_l = Pw + (size_t)L * DIM * DIM;
    const float* Pb_l = Pb + L * DIM;
    const float* F1w_l = F1w + (size_t)L * DIM * HID;
    const float* F1b_l = F1b + L * HID;
    const float* F2w_l = F2w + (size_t)L * HID * DIM;
    const float* F2b_l = F2b + L * DIM;

    // ---- LN1: sx -> sa1 (all 8 waves)
    ln_rows(sx, sa1, L1w + L * DIM, L1b + L * DIM, wave, 8, lane);
    __syncthreads();

    // ---- Jqkv GEMM (waves 0-5) overlapped with LN2 (waves 6-7: srel -> sa2)
    if (wave < 6) {
      gemm384(sa1, Jw_l, Jb_l, sqJ, t);
    } else {
      ln_rows(srel, sa2, L2w + L * DIM, L2b + L * DIM, wave - 6, 2, lane);
    }
    __syncthreads();

    // ---- Iqk GEMM (waves 0-5)
    if (wave < 6) gemm384(sa2, Iw_l, Ib_l, sqI, t);
    __syncthreads();

    // ---- scores: sc[h][n][m] = (Jq.Jk + Iq.Ik + Iv@Cw + Cb) * SCALE
    for (int idx = t; idx < NH * NJ * NJ; idx += NT) {
      int h = idx / (NJ * NJ);
      int r = idx - h * (NJ * NJ);
      int n = r / NJ;
      int m = r - n * NJ;
      const int hc = h * HSZ;
      float s = 0.f;
#pragma unroll
      for (int d = 0; d < HSZ; ++d) {
        s += sqJ[n][hc + d] * sqJ[m][DIM + hc + d];
        s += sqI[n][hc + d] * sqI[m][DIM + hc + d];
        s += sqI[n][2 * DIM + hc + d] * Cw_l[d * NJ + m];
      }
      ssc[h][n][m] = (s + Cb_l[m]) * QK_SCALE;
    }
    __syncthreads();

    // ---- softmax over m (one thread per (h,n) row)
    if (t < NH * NJ) {
      int h = t / NJ, n = t - h * NJ;
      float* row = ssc[h][n];
      float mx = row[0];
#pragma unroll
      for (int m = 1; m < NJ; ++m) mx = fmaxf(mx, row[m]);
      float ssum = 0.f;
#pragma unroll
      for (int m = 0; m < NJ; ++m) {
        float e = __expf(row[m] - mx);
        row[m] = e;
        ssum += e;
      }
      float inv = 1.0f / ssum;
#pragma unroll
      for (int m = 0; m < NJ; ++m) row[m] *= inv;
    }
    __syncthreads();

    // ---- PV: sy[n][c] = sum_m prob[h][n][m] * Jv[m][c]   (c = h*8+d)
    for (int idx = t; idx < NJ * DIM; idx += NT) {
      int n = idx >> 7;
      int c = idx & (DIM - 1);
      int h = c >> 3;
      float s = 0.f;
#pragma unroll
      for (int m = 0; m < NJ; ++m) s += ssc[h][n][m] * sqJ[m][2 * DIM + c];
      sy[n][c] = s;
    }
    __syncthreads();

    // ---- proj + residual: sx += sy @ Pw + Pb  (128 cols x 4 row-groups)
    {
      int j = t & (DIM - 1);
      int g = t >> 7;  // 0..3 -> rows g, g+4, g+8, (g+12 if <15)
      float acc0 = 0, acc1 = 0, acc2 = 0, acc3 = 0;
#pragma unroll 2
      for (int k = 0; k < DIM; k += 4) {
        float w0 = Pw_l[(k + 0) * DIM + j];
        float w1 = Pw_l[(k + 1) * DIM + j];
        float w2 = Pw_l[(k + 2) * DIM + j];
        float w3 = Pw_l[(k + 3) * DIM + j];
        float4 a0 = *reinterpret_cast<const float4*>(&sy[g][k]);
        acc0 += a0.x * w0 + a0.y * w1 + a0.z * w2 + a0.w * w3;
        float4 a1 = *reinterpret_cast<const float4*>(&sy[g + 4][k]);
        acc1 += a1.x * w0 + a1.y * w1 + a1.z * w2 + a1.w * w3;
        float4 a2 = *reinterpret_cast<const float4*>(&sy[g + 8][k]);
        acc2 += a2.x * w0 + a2.y * w1 + a2.z * w2 + a2.w * w3;
        if (g < 3) {
          float4 a3 = *reinterpret_cast<const float4*>(&sy[g + 12][k]);
          acc3 += a3.x * w0 + a3.y * w1 + a3.z * w2 + a3.w * w3;
        }
      }
      float bj = Pb_l[j];
      sx[g][j] += acc0 + bj;
      sx[g + 4][j] += acc1 + bj;
      sx[g + 8][j] += acc2 + bj;
      if (g < 3) sx[g + 12][j] += acc3 + bj;
    }
    __syncthreads();

    // ---- LN3: sx -> sa1
    ln_rows(sx, sa1, L3w + L * DIM, L3b + L * DIM, wave, 8, lane);
    __syncthreads();

    // ---- fc1 + exact GELU: sh1 = gelu(sa1 @ F1w + b)  (64 cols x 8 row-groups)
    {
      int j = t & (HID - 1);
      int g = wave;  // rows g, g+8 (if < 15)
      float acc0 = 0, acc1 = 0;
#pragma unroll 2
      for (int k = 0; k < DIM; k += 4) {
        float w0 = F1w_l[(k + 0) * HID + j];
        float w1 = F1w_l[(k + 1) * HID + j];
        float w2 = F1w_l[(k + 2) * HID + j];
        float w3 = F1w_l[(k + 3) * HID + j];
        float4 a0 = *reinterpret_cast<const float4*>(&sa1[g][k]);
        acc0 += a0.x * w0 + a0.y * w1 + a0.z * w2 + a0.w * w3;
        if (g < 7) {
          float4 a1 = *reinterpret_cast<const float4*>(&sa1[g + 8][k]);
          acc1 += a1.x * w0 + a1.y * w1 + a1.z * w2 + a1.w * w3;
        }
      }
      float bj = F1b_l[j];
      float x0 = acc0 + bj;
      sh1[g][j] = 0.5f * x0 * (1.0f + erff(x0 * 0.70710678118654752f));
      if (g < 7) {
        float x1 = acc1 + bj;
        sh1[g + 8][j] = 0.5f * x1 * (1.0f + erff(x1 * 0.70710678118654752f));
      }
    }
    __syncthreads();

    // ---- fc2 + residual: sx += sh1 @ F2w + b  (128 cols x 4 row-groups)
    {
      int j = t & (DIM - 1);
      int g = t >> 7;
      float acc0 = 0, acc1 = 0, acc2 = 0, acc3 = 0;
#pragma unroll 2
      for (int k = 0; k < HID; k += 4) {
        float w0 = F2w_l[(k + 0) * DIM + j];
        float w1 = F2w_l[(k + 1) * DIM + j];
        float w2 = F2w_l[(k + 2) * DIM + j];
        float w3 = F2w_l[(k + 3) * DIM + j];
        float4 a0 = *reinterpret_cast<const float4*>(&sh1[g][k]);
        acc0 += a0.x * w0 + a0.y * w1 + a0.z * w2 + a0.w * w3;
        float4 a1 = *reinterpret_cast<const float4*>(&sh1[g + 4][k]);
        acc1 += a1.x * w0 + a1.y * w1 + a1.z * w2 + a1.w * w3;
        float4 a2 = *reinterpret_cast<const float4*>(&sh1[g + 8][k]);
        acc2 += a2.x * w0 + a2.y * w1 + a2.z * w2 + a2.w * w3;
        if (g < 3) {
          float4 a3 = *reinterpret_cast<const float4*>(&sh1[g + 12][k]);
          acc3 += a3.x * w0 + a3.y * w1 + a3.z * w2 + a3.w * w3;
        }
      }
      float bj = F2b_l[j];
      sx[g][j] += acc0 + bj;
      sx[g + 4][j] += acc1 + bj;
      sx[g + 8][j] += acc2 + bj;
      if (g < 3) sx[g + 12][j] += acc3 + bj;
    }
    __syncthreads();
  }

  // ---- write result
  {
    float* op = out + (size_t)b * (NJ * DIM);
    const float* xflat = &sx[0][0];
    for (int i = t; i < NJ * DIM; i += NT) op[i] = xflat[i];
  }
}

extern "C" void kernel_launch(void* const* d_in, const int* in_sizes, int n_in,
                              void* d_out, int out_size, void* d_ws, size_t ws_size,
                              hipStream_t stream) {
  const float* jf = (const float*)d_in[0];
  const float* rf = (const float*)d_in[1];
  const float* Jw = (const float*)d_in[2];
  const float* Jb = (const float*)d_in[3];
  const float* Iw = (const float*)d_in[4];
  const float* Ib = (const float*)d_in[5];
  const float* Cw = (const float*)d_in[6];
  const float* Cb = (const float*)d_in[7];
  const float* Pw = (const float*)d_in[8];
  const float* Pb = (const float*)d_in[9];
  const float* L1w = (const float*)d_in[10];
  const float* L1b = (const float*)d_in[11];
  const float* L2w = (const float*)d_in[12];
  const float* L2b = (const float*)d_in[13];
  const float* L3w = (const float*)d_in[14];
  const float* L3b = (const float*)d_in[15];
  const float* F1w = (const float*)d_in[16];
  const float* F1b = (const float*)d_in[17];
  const float* F2w = (const float*)d_in[18];
  const float* F2b = (const float*)d_in[19];
  float* out = (float*)d_out;

  hipLaunchKernelGGL(jrt_fused, dim3(NBATCH), dim3(NT), 0, stream, jf, rf, Jw, Jb,
                     Iw, Ib, Cw, Cb, Pw, Pb, L1w, L1b, L2w, L2b, L3w, L3b, F1w, F1b,
                     F2w, F2b, out);
}

// Round 4
// 2969.020 us; speedup vs baseline: 5.9427x; 5.9427x over previous
//
#include <hip/hip_runtime.h>
#include <hip/hip_bf16.h>
#include <math.h>

typedef __attribute__((ext_vector_type(4)))  float        f32x4;
typedef __attribute__((ext_vector_type(16))) float        f32x16;
typedef __attribute__((ext_vector_type(8)))  short        s16x8;
typedef __attribute__((ext_vector_type(4)))  unsigned int u32x4;
typedef __attribute__((ext_vector_type(2)))  unsigned int u32x2;

// ---------------- LDS layout (bytes) ----------------
// sA1 [128]x256B jn | sA2 rn | sQJ [128]x128B (Jq|Jk quarter) | sQI [128]x192B (Iq|Ik|Iv)
// sVt [40]x256B (v^T, rows=ch-local, +8 zero pad rows) | sy [128]x256B attn-out
// spr aliases sQJ+sQI | sh1 aliases sy | P: 8 waves x [16]x80B | CwT [16]x16B | zeros
#define OFF_A1  0
#define OFF_A2  32768
#define OFF_QJ  65536
#define OFF_QI  81920
#define OFF_VT  106496
#define OFF_SY  116736
#define OFF_SPR 65536
#define OFF_H1  116736
#define OFF_P   149504
#define OFF_CWT 159744
#define OFF_Z   160000
#define LDS_TOTAL 160256

__device__ __forceinline__ unsigned short f2bfu(float f){
  unsigned u = __builtin_bit_cast(unsigned, f);
  return (unsigned short)((u + 0x7FFFu + ((u >> 16) & 1u)) >> 16);   // RNE, finite inputs
}
__device__ __forceinline__ unsigned pkbf(float a, float b){
  return (unsigned)f2bfu(a) | ((unsigned)f2bfu(b) << 16);
}
__device__ __forceinline__ float bflo(unsigned u){ return __builtin_bit_cast(float, u << 16); }
__device__ __forceinline__ float bfhi(unsigned u){ return __builtin_bit_cast(float, u & 0xFFFF0000u); }

template<int CTRL>
__device__ __forceinline__ float dppf(float v){
  return __builtin_bit_cast(float,
    __builtin_amdgcn_update_dpp(0, __builtin_bit_cast(int, v), CTRL, 0xF, 0xF, true));
}
// reductions over the 16-lane DPP "row" (= our m-dimension) via row_ror 8/4/2/1
__device__ __forceinline__ float rmax16(float v){
  v = fmaxf(v, dppf<0x128>(v)); v = fmaxf(v, dppf<0x124>(v));
  v = fmaxf(v, dppf<0x122>(v)); v = fmaxf(v, dppf<0x121>(v)); return v;
}
__device__ __forceinline__ float rsum16(float v){
  v += dppf<0x128>(v); v += dppf<0x124>(v); v += dppf<0x122>(v); v += dppf<0x121>(v); return v;
}
// sum over 4 lanes of one LN row (lane bits 0-1) via quad_perm xor1, xor2
__device__ __forceinline__ float qsum4(float v){
  v += dppf<0xB1>(v); v += dppf<0x4E>(v); return v;
}
__device__ __forceinline__ int swzQI(int chunk, int row){
  return (chunk < 8) ? (chunk ^ (row & 7)) : (8 + ((chunk - 8) ^ (row & 3)));
}
__device__ __forceinline__ f32x16 mfma32(u32x4 a, u32x4 b, f32x16 c){
  return __builtin_amdgcn_mfma_f32_32x32x16_bf16(
    __builtin_bit_cast(s16x8, a), __builtin_bit_cast(s16x8, b), c, 0, 0, 0);
}
__device__ __forceinline__ f32x4 mfma16x(u32x4 a, u32x4 b, f32x4 c){
  return __builtin_amdgcn_mfma_f32_16x16x32_bf16(
    __builtin_bit_cast(s16x8, a), __builtin_bit_cast(s16x8, b), c, 0, 0, 0);
}

// ---- LayerNorm from 32 per-thread values -> bf16 swizzled LDS buffer (rowB=256, 16 chunks)
__device__ __forceinline__ void ln_store(char* sm, int OFF, const float* v,
                                         const float* wp, const float* bp, int r, int q){
  float s = 0.f, s2 = 0.f;
#pragma unroll
  for (int i = 0; i < 32; ++i){ s += v[i]; s2 += v[i]*v[i]; }
  s = qsum4(s); s2 = qsum4(s2);
  float mean = s * (1.f/128.f);
  float var  = fmaxf(s2 * (1.f/128.f) - mean*mean, 0.f);
  float rstd = rsqrtf(var + 1e-5f);
  const float4* w4 = (const float4*)wp + q*8;
  const float4* b4 = (const float4*)bp + q*8;
#pragma unroll
  for (int j = 0; j < 4; ++j){
    float4 wa = w4[2*j], wb = w4[2*j+1], ba = b4[2*j], bb = b4[2*j+1];
    float o0 = (v[8*j+0]-mean)*rstd*wa.x + ba.x;
    float o1 = (v[8*j+1]-mean)*rstd*wa.y + ba.y;
    float o2 = (v[8*j+2]-mean)*rstd*wa.z + ba.z;
    float o3 = (v[8*j+3]-mean)*rstd*wa.w + ba.w;
    float o4 = (v[8*j+4]-mean)*rstd*wb.x + bb.x;
    float o5 = (v[8*j+5]-mean)*rstd*wb.y + bb.y;
    float o6 = (v[8*j+6]-mean)*rstd*wb.z + bb.z;
    float o7 = (v[8*j+7]-mean)*rstd*wb.w + bb.w;
    u32x4 pk; pk.x = pkbf(o0,o1); pk.y = pkbf(o2,o3); pk.z = pkbf(o4,o5); pk.w = pkbf(o6,o7);
    *(u32x4*)(sm + OFF + r*256 + (((4*q + j) ^ (r & 15)) << 4)) = pk;
  }
}

// ---- swapped GEMM unit: D[ch32][n] = W^T(ch rows) . act(sA)  -> write-T joint-major dst
__device__ __forceinline__ void gemm_swapped_unit(char* sm, const unsigned short* wsrc,
    const float* biasp, int aOFF, int dstOFF, int dstRowB, int qiMode, int colbase, int l){
  const int l31 = l & 31, G = l >> 5;
  u32x4 af[8];
#pragma unroll
  for (int kt = 0; kt < 8; ++kt)
    af[kt] = *(const u32x4*)((const char*)wsrc + l31*256 + kt*32 + G*16);
  float bias[16];
#pragma unroll
  for (int rg = 0; rg < 4; ++rg)
#pragma unroll
    for (int i = 0; i < 4; ++i) bias[rg*4+i] = biasp[rg*8 + G*4 + i];
  f32x16 acc[4];
#pragma unroll
  for (int nt = 0; nt < 4; ++nt)
#pragma unroll
    for (int i = 0; i < 16; ++i) acc[nt][i] = 0.f;
#pragma unroll
  for (int kt = 0; kt < 8; ++kt){
#pragma unroll
    for (int nt = 0; nt < 4; ++nt){
      int row = nt*32 + l31;
      u32x4 bf = *(const u32x4*)(sm + aOFF + row*256 + (((2*kt + G) ^ (row & 15)) << 4));
      acc[nt] = mfma32(af[kt], bf, acc[nt]);
    }
  }
#pragma unroll
  for (int nt = 0; nt < 4; ++nt){
    int drow = nt*32 + l31;
#pragma unroll
    for (int rg = 0; rg < 4; ++rg){
      unsigned lo = pkbf(acc[nt][rg*4+0] + bias[rg*4+0], acc[nt][rg*4+1] + bias[rg*4+1]);
      unsigned hi = pkbf(acc[nt][rg*4+2] + bias[rg*4+2], acc[nt][rg*4+3] + bias[rg*4+3]);
      int chunk = (colbase >> 3) + rg;
      int pc = qiMode ? swzQI(chunk, drow) : (chunk ^ (drow & 7));
      u32x2 v; v.x = lo; v.y = hi;
      *(u32x2*)(sm + dstOFF + drow*dstRowB + pc*16 + G*8) = v;
    }
  }
}

// ---- Jv unit (unswapped): D[n][c] = jn . Wv  -> write-T channel-major sVt[c][n]
__device__ __forceinline__ void gemm_jv_unit(char* sm, const unsigned short* wsrc,
                                             const float* biasp, int l){
  const int l31 = l & 31, G = l >> 5;
  u32x4 bfw[8];
#pragma unroll
  for (int kt = 0; kt < 8; ++kt)
    bfw[kt] = *(const u32x4*)((const char*)wsrc + l31*256 + kt*32 + G*16);
  float bv = biasp[l31];
  f32x16 acc[4];
#pragma unroll
  for (int nt = 0; nt < 4; ++nt)
#pragma unroll
    for (int i = 0; i < 16; ++i) acc[nt][i] = 0.f;
#pragma unroll
  for (int kt = 0; kt < 8; ++kt){
#pragma unroll
    for (int nt = 0; nt < 4; ++nt){
      int row = nt*32 + l31;
      u32x4 afr = *(const u32x4*)(sm + OFF_A1 + row*256 + (((2*kt + G) ^ (row & 15)) << 4));
      acc[nt] = mfma32(afr, bfw[kt], acc[nt]);
    }
  }
#pragma unroll
  for (int nt = 0; nt < 4; ++nt){
#pragma unroll
    for (int rg = 0; rg < 4; ++rg){
      unsigned lo = pkbf(acc[nt][rg*4+0] + bv, acc[nt][rg*4+1] + bv);
      unsigned hi = pkbf(acc[nt][rg*4+2] + bv, acc[nt][rg*4+3] + bv);
      int chunk = nt*4 + rg;
      int pc = chunk ^ (l31 & 15);
      u32x2 v; v.x = lo; v.y = hi;
      *(u32x2*)(sm + OFF_VT + l31*256 + pc*16 + G*8) = v;
    }
  }
}

// ---- proj / fc2: swapped, 2 n32-tiles per wave, write-T -> spr
template<int NKT>
__device__ __forceinline__ void gemm_out2(char* sm, const unsigned short* wsrc, int wRowB,
    const float* biasp, int srcOFF, int srcRowB, int srcMask, int nt0, int dstColBase, int l){
  const int l31 = l & 31, G = l >> 5;
  u32x4 af[NKT];
#pragma unroll
  for (int kt = 0; kt < NKT; ++kt)
    af[kt] = *(const u32x4*)((const char*)wsrc + l31*wRowB + kt*32 + G*16);
  float bias[16];
#pragma unroll
  for (int rg = 0; rg < 4; ++rg)
#pragma unroll
    for (int i = 0; i < 4; ++i) bias[rg*4+i] = biasp[rg*8 + G*4 + i];
  f32x16 acc[2];
#pragma unroll
  for (int j = 0; j < 2; ++j)
#pragma unroll
    for (int i = 0; i < 16; ++i) acc[j][i] = 0.f;
#pragma unroll
  for (int kt = 0; kt < NKT; ++kt){
#pragma unroll
    for (int j = 0; j < 2; ++j){
      int row = (nt0+j)*32 + l31;
      u32x4 bf = *(const u32x4*)(sm + srcOFF + row*srcRowB + (((2*kt + G) ^ (row & srcMask)) << 4));
      acc[j] = mfma32(af[kt], bf, acc[j]);
    }
  }
#pragma unroll
  for (int j = 0; j < 2; ++j){
    int drow = (nt0+j)*32 + l31;
#pragma unroll
    for (int rg = 0; rg < 4; ++rg){
      unsigned lo = pkbf(acc[j][rg*4+0] + bias[rg*4+0], acc[j][rg*4+1] + bias[rg*4+1]);
      unsigned hi = pkbf(acc[j][rg*4+2] + bias[rg*4+2], acc[j][rg*4+3] + bias[rg*4+3]);
      int chunk = (dstColBase >> 3) + rg;
      int pc = chunk ^ (drow & 15);
      u32x2 v; v.x = lo; v.y = hi;
      *(u32x2*)(sm + OFF_SPR + drow*256 + pc*16 + G*8) = v;
    }
  }
}

// ---- fc1: swapped, 1 tile, bias + exact GELU, write-T -> sh1
__device__ __forceinline__ void gemm_fc1(char* sm, const unsigned short* wsrc,
                                         const float* biasp, int nt, int colbase, int l){
  const int l31 = l & 31, G = l >> 5;
  u32x4 af[8];
#pragma unroll
  for (int kt = 0; kt < 8; ++kt)
    af[kt] = *(const u32x4*)((const char*)wsrc + l31*256 + kt*32 + G*16);
  float bias[16];
#pragma unroll
  for (int rg = 0; rg < 4; ++rg)
#pragma unroll
    for (int i = 0; i < 4; ++i) bias[rg*4+i] = biasp[rg*8 + G*4 + i];
  f32x16 acc;
#pragma unroll
  for (int i = 0; i < 16; ++i) acc[i] = 0.f;
#pragma unroll
  for (int kt = 0; kt < 8; ++kt){
    int row = nt*32 + l31;
    u32x4 bf = *(const u32x4*)(sm + OFF_A1 + row*256 + (((2*kt + G) ^ (row & 15)) << 4));
    acc = mfma32(af[kt], bf, acc);
  }
  int drow = nt*32 + l31;
#pragma unroll
  for (int rg = 0; rg < 4; ++rg){
    float g[4];
#pragma unroll
    for (int i = 0; i < 4; ++i){
      float xx = acc[rg*4+i] + bias[rg*4+i];
      g[i] = 0.5f * xx * (1.f + erff(xx * 0.70710678118654752f));
    }
    unsigned lo = pkbf(g[0], g[1]), hi = pkbf(g[2], g[3]);
    int chunk = (colbase >> 3) + rg;
    int pc = chunk ^ (drow & 7);
    u32x2 v; v.x = lo; v.y = hi;
    *(u32x2*)(sm + OFF_H1 + drow*128 + pc*16 + G*8) = v;
  }
}

// ---- weight prep: fp32 -> bf16, transposed [out][in], per-layer block of 131072 elems
__global__ void jrt_prep(const float* __restrict__ Jw, const float* __restrict__ Iw,
                         const float* __restrict__ Pw, const float* __restrict__ F1,
                         const float* __restrict__ F2, unsigned short* __restrict__ ws){
  int e = blockIdx.x * 256 + threadIdx.x;
  if (e >= 786432) return;
  int L = e >> 17, r = e & 131071;
  float v;
  if      (r <  32768){ int o = r>>7,          i = r&127;  v = Jw[(L*128+i)*384 + o]; }
  else if (r <  49152){ int r2=r-32768,  o=r2>>7, i=r2&127; v = Jw[(L*128+i)*384 + 256 + o]; }
  else if (r <  98304){ int r2=r-49152,  o=r2>>7, i=r2&127; v = Iw[(L*128+i)*384 + o]; }
  else if (r < 114688){ int r2=r-98304,  o=r2>>7, i=r2&127; v = Pw[(L*128+i)*128 + o]; }
  else if (r < 122880){ int r2=r-114688, o=r2>>7, i=r2&127; v = F1[(L*128+i)*64  + o]; }
  else                { int r2=r-122880, o=r2>>6, i=r2&63;  v = F2[(L*64 +i)*128 + o]; }
  ws[e] = f2bfu(v);
}

__global__ __launch_bounds__(512, 2) void jrt_main(
    const float* __restrict__ jf, const float* __restrict__ rf,
    const float* __restrict__ Jb, const float* __restrict__ Ib,
    const float* __restrict__ Cw, const float* __restrict__ Cb,
    const float* __restrict__ Pb,
    const float* __restrict__ L1w, const float* __restrict__ L1b,
    const float* __restrict__ L2w, const float* __restrict__ L2b,
    const float* __restrict__ L3w, const float* __restrict__ L3b,
    const float* __restrict__ F1b, const float* __restrict__ F2b,
    const unsigned short* __restrict__ ws, float* __restrict__ out){
  extern __shared__ char sm[];
  const int t = threadIdx.x, l = t & 63, w = t >> 6, b = blockIdx.x;
  const int r_own = t >> 2, q_own = t & 3;
  const int br_own = r_own >> 4, jj_own = r_own & 15;
  const bool live = (jj_own < 15);
  const int grow = (b*8 + br_own)*15 + jj_own;

  // zero scratch: P tiles (incl. padded cols), zeros page, sVt pad rows 32-39
  for (int i = t; i < 10240/4; i += 512) ((int*)(sm + OFF_P))[i] = 0;
  if (t < 64) ((int*)(sm + OFF_Z))[t] = 0;
  for (int i = t; i < 2048/4; i += 512) ((int*)(sm + OFF_VT + 8192))[i] = 0;

  float x[32];
  if (live){
#pragma unroll
    for (int j = 0; j < 8; ++j){
      float4 v4 = *(const float4*)(jf + (size_t)grow*128 + q_own*32 + 4*j);
      x[4*j+0]=v4.x; x[4*j+1]=v4.y; x[4*j+2]=v4.z; x[4*j+3]=v4.w;
    }
  } else {
#pragma unroll
    for (int i = 0; i < 32; ++i) x[i] = 0.f;
  }
  __syncthreads();

  for (int L = 0; L < 6; ++L){
    const int Lw = L * 131072;
    const float* Jb_l  = Jb  + L*384;
    const float* Ib_l  = Ib  + L*384;
    const float* Pb_l  = Pb  + L*128;
    const float* F1b_l = F1b + L*64;
    const float* F2b_l = F2b + L*128;

    // ---- P0: LN1(x)->sA1, LN2(rel)->sA2, CwT build
    ln_store(sm, OFF_A1, x, L1w + L*128, L1b + L*128, r_own, q_own);
    {
      float v[32];
      if (live){
#pragma unroll
        for (int j = 0; j < 8; ++j){
          float4 v4 = *(const float4*)(rf + (size_t)grow*128 + q_own*32 + 4*j);
          v[4*j+0]=v4.x; v[4*j+1]=v4.y; v[4*j+2]=v4.z; v[4*j+3]=v4.w;
        }
      } else {
#pragma unroll
        for (int i = 0; i < 32; ++i) v[i] = 0.f;
      }
      ln_store(sm, OFF_A2, v, L2w + L*128, L2b + L*128, r_own, q_own);
    }
    if (t < 128){
      int mm = t >> 3, dd = t & 7;
      float cv = (mm < 15) ? Cw[(L*8 + dd)*15 + mm] : 0.f;
      *(unsigned short*)(sm + OFF_CWT + mm*16 + dd*2) = f2bfu(cv);
    }
    __syncthreads();

    const float cbm = ((l & 15) < 15) ? Cb[L*15 + (l & 15)] : 0.f;

    // ---- head-quarter pipeline
    for (int Q = 0; Q < 4; ++Q){
      if (w < 6){
        if (w == 2){
          gemm_jv_unit(sm, ws + Lw + 32768 + (32*Q)*128, Jb_l + 256 + 32*Q, l);
        } else if (w < 2){
          const int cb = (w == 0) ? 32*Q : 128 + 32*Q;
          gemm_swapped_unit(sm, ws + Lw + cb*128, Jb_l + cb,
                            OFF_A1, OFF_QJ, 128, 0, (w == 0) ? 0 : 32, l);
        } else {
          const int u = w - 3;
          const int cb = u*128 + 32*Q;
          gemm_swapped_unit(sm, ws + Lw + 49152 + cb*128, Ib_l + cb,
                            OFF_A2, OFF_QI, 192, 1, u*32, l);
        }
      }
      __syncthreads();

      // attention for this quarter: wave w = batch-row w, heads h=0..3 (global 4Q+h)
      {
        const int m = l & 15, G = l >> 4;
        const int r = w*16 + m;
        const int c7 = r & 7, c3 = r & 3;
        f32x4 zc = {0.f, 0.f, 0.f, 0.f};
#pragma unroll
        for (int h = 0; h < 4; ++h){
          int aoff = (G == 0) ? OFF_QJ + r*128 + ((h ^ c7) << 4)
                   : (G == 1) ? OFF_QI + r*192 + ((h ^ c7) << 4)
                   : (G == 2) ? OFF_QI + r*192 + ((8 + (h ^ c3)) << 4)
                              : OFF_Z;
          int boff = (G == 0) ? OFF_QJ + r*128 + (((4+h) ^ c7) << 4)
                   : (G == 1) ? OFF_QI + r*192 + (((4+h) ^ c7) << 4)
                   : (G == 2) ? OFF_CWT + m*16
                              : OFF_Z;
          u32x4 qa = *(const u32x4*)(sm + aoff);
          u32x4 kb = *(const u32x4*)(sm + boff);
          f32x4 sc = mfma16x(qa, kb, zc);   // D[n][m]: Jq.Jk + Iq.Ik + Iv.Cw
          float p[4];
#pragma unroll
          for (int i = 0; i < 4; ++i){
            float sv = (m == 15) ? -3.0e38f : (sc[i] + cbm) * 0.6f;
            float mx = rmax16(sv);
            float e  = __expf(sv - mx);
            float su = rsum16(e);
            p[i] = e / su;
          }
#pragma unroll
          for (int i = 0; i < 4; ++i)
            *(unsigned short*)(sm + OFF_P + w*1280 + (G*4 + i)*80 + m*2) = f2bfu(p[i]);
          int vrow = 8*h + m;
          int voff = (G < 2) ? OFF_VT + vrow*256 + (((2*w + G) ^ (vrow & 15)) << 4) : OFF_Z;
          u32x4 va = *(const u32x4*)(sm + voff);
          u32x4 pbf = *(const u32x4*)(sm + OFF_P + w*1280 + m*80 + G*16);
          f32x4 o = mfma16x(va, pbf, zc);   // D[c][n] = Vt . P^T
          if (G < 2){
            u32x2 vv; vv.x = pkbf(o[0], o[1]); vv.y = pkbf(o[2], o[3]);
            *(u32x2*)(sm + OFF_SY + r*256 + (((4*Q + h) ^ m) << 4) + G*8) = vv;
          }
        }
      }
      __syncthreads();
    }

    // ---- proj -> spr
    gemm_out2<8>(sm, ws + Lw + 98304 + (32*(w&3))*128, 256, Pb_l + 32*(w&3),
                 OFF_SY, 256, 15, (w>>2)*2, 32*(w&3), l);
    __syncthreads();

    // ---- residual + LN3
    if (live){
#pragma unroll
      for (int j = 0; j < 4; ++j){
        u32x4 v = *(const u32x4*)(sm + OFF_SPR + r_own*256 + (((4*q_own + j) ^ (r_own & 15)) << 4));
        x[j*8+0] += bflo(v.x); x[j*8+1] += bfhi(v.x);
        x[j*8+2] += bflo(v.y); x[j*8+3] += bfhi(v.y);
        x[j*8+4] += bflo(v.z); x[j*8+5] += bfhi(v.z);
        x[j*8+6] += bflo(v.w); x[j*8+7] += bfhi(v.w);
      }
    }
    ln_store(sm, OFF_A1, x, L3w + L*128, L3b + L*128, r_own, q_own);
    __syncthreads();

    // ---- fc1 (+GELU) -> sh1
    gemm_fc1(sm, ws + Lw + 114688 + (32*(w&1))*128, F1b_l + 32*(w&1), w>>1, 32*(w&1), l);
    __syncthreads();

    // ---- fc2 -> spr
    gemm_out2<4>(sm, ws + Lw + 122880 + (32*(w&3))*64, 128, F2b_l + 32*(w&3),
                 OFF_H1, 128, 7, (w>>2)*2, 32*(w&3), l);
    __syncthreads();

    // ---- residual
    if (live){
#pragma unroll
      for (int j = 0; j < 4; ++j){
        u32x4 v = *(const u32x4*)(sm + OFF_SPR + r_own*256 + (((4*q_own + j) ^ (r_own & 15)) << 4));
        x[j*8+0] += bflo(v.x); x[j*8+1] += bfhi(v.x);
        x[j*8+2] += bflo(v.y); x[j*8+3] += bfhi(v.y);
        x[j*8+4] += bflo(v.z); x[j*8+5] += bfhi(v.z);
        x[j*8+6] += bflo(v.w); x[j*8+7] += bfhi(v.w);
      }
    }
    // next iteration's LN1/LN2 writes are barrier-protected by the P0-end barrier
  }

  if (live){
#pragma unroll
    for (int j = 0; j < 8; ++j){
      float4 v4; v4.x = x[4*j+0]; v4.y = x[4*j+1]; v4.z = x[4*j+2]; v4.w = x[4*j+3];
      *(float4*)(out + (size_t)grow*128 + q_own*32 + 4*j) = v4;
    }
  }
}

extern "C" void kernel_launch(void* const* d_in, const int* in_sizes, int n_in,
                              void* d_out, int out_size, void* d_ws, size_t ws_size,
                              hipStream_t stream){
  const float* jf  = (const float*)d_in[0];
  const float* rfp = (const float*)d_in[1];
  const float* Jw  = (const float*)d_in[2];
  const float* Jb  = (const float*)d_in[3];
  const float* Iw  = (const float*)d_in[4];
  const float* Ib  = (const float*)d_in[5];
  const float* Cw  = (const float*)d_in[6];
  const float* Cb  = (const float*)d_in[7];
  const float* Pw  = (const float*)d_in[8];
  const float* Pb  = (const float*)d_in[9];
  const float* L1w = (const float*)d_in[10];
  const float* L1b = (const float*)d_in[11];
  const float* L2w = (const float*)d_in[12];
  const float* L2b = (const float*)d_in[13];
  const float* L3w = (const float*)d_in[14];
  const float* L3b = (const float*)d_in[15];
  const float* F1w = (const float*)d_in[16];
  const float* F1b = (const float*)d_in[17];
  const float* F2w = (const float*)d_in[18];
  const float* F2b = (const float*)d_in[19];
  float* outp = (float*)d_out;
  unsigned short* wsb = (unsigned short*)d_ws;

  hipFuncSetAttribute(reinterpret_cast<const void*>(jrt_main),
                      hipFuncAttributeMaxDynamicSharedMemorySize, LDS_TOTAL);

  jrt_prep<<<3072, 256, 0, stream>>>(Jw, Iw, Pw, F1w, F2w, wsb);
  jrt_main<<<2048, 512, LDS_TOTAL, stream>>>(jf, rfp, Jb, Ib, Cw, Cb, Pb,
                                             L1w, L1b, L2w, L2b, L3w, L3b,
                                             F1b, F2b, wsb, outp);
}